// Round 1
// baseline (194.435 us; speedup 1.0000x reference)
//
#include <hip/hip_runtime.h>

// Q6ArithmeticLayer: out = softmax(-hs * 3*(1 - dot(normalize(tanh(x@W^T)), normalize(P))))
// x: (32768, 1024) fp32 -> 134 MB stream (roofline ~21 us @ 6.3 TB/s).
// R3: occupancy attack. Old kernel: wreg 96 VGPR + xv 64 VGPR under
// __launch_bounds__(256,2) -> 2 waves/SIMD (25% occ), 0.7 TB/s => latency-bound.
//   - W now staged once per block into LDS (24 KB), read per j-chunk as
//     ds_read_b128 (6 float4 live at a time = 24 VGPRs instead of 96).
//   - __launch_bounds__(256,3): cap ~170 VGPRs -> 12 waves/CU (1.5x occ).
//   - blocks=1024: each wave runs 2 iterations (8 tokens) so iter-2 loads
//     overlap iter-1 reduction/epilogue, and W staging amortizes.
//   - reduction unchanged: xor32 token-pair scatter (12 shfl) + xor16 (6) +
//     xor{8,4,2,1} butterfly (24) = 42 shfl / 4 tokens.

#define DIM 1024
#define NK 6
#define NPROTO 8
#define TPI 4  // tokens per wave iteration

__global__ __launch_bounds__(256, 3) void q6_fused_kernel(
    const float* __restrict__ x,
    const float* __restrict__ W,
    const float* __restrict__ protos,
    const float* __restrict__ hs_ptr,
    float* __restrict__ out,
    int n_tokens, int n_waves)
{
    const int tid  = threadIdx.x;
    const int lane = tid & 63;
    const int wave_id = blockIdx.x * (blockDim.x >> 6) + (tid >> 6);

    // --- stage W into LDS once per block: 6 x 1024 fp32 = 24 KB, coalesced ---
    __shared__ float4 wlds[NK * (DIM / 4)];   // 1536 float4
#pragma unroll
    for (int i = 0; i < (NK * DIM / 4) / 256; ++i)   // 6 iterations
        wlds[i * 256 + tid] = reinterpret_cast<const float4*>(W)[i * 256 + tid];

    // --- normalized prototype for this lane's proto slot (while W stage in flight) ---
    const int pl = lane & 7;
    float p[NK];
#pragma unroll
    for (int k = 0; k < NK; ++k) p[k] = protos[pl * NK + k];
    {
        float pn = sqrtf(p[0]*p[0] + p[1]*p[1] + p[2]*p[2] + p[3]*p[3] + p[4]*p[4] + p[5]*p[5]);
        float inv = 1.0f / fmaxf(pn, 1e-12f);
#pragma unroll
        for (int k = 0; k < NK; ++k) p[k] *= inv;
    }
    const float hs = hs_ptr[0];

    __syncthreads();

    const bool hi5 = (lane & 32) != 0;
    const bool hi4 = (lane & 16) != 0;
    const int tloc = lane >> 4;   // which of the 4 tokens this 16-lane group owns
    const int pidx = lane & 15;   // proto slot within the group (active if <8)

    for (int tb = wave_id * TPI; tb < n_tokens; tb += n_waves * TPI) {
        // ---- load x for 4 tokens: 16 x global_load_dwordx4, all in flight ----
        float4 xv[TPI][4];
#pragma unroll
        for (int t = 0; t < TPI; ++t) {
            const float* xt = x + (size_t)(tb + t) * DIM;
#pragma unroll
            for (int j = 0; j < 4; ++j)
                xv[t][j] = *reinterpret_cast<const float4*>(&xt[j * 256 + lane * 4]);
        }

        // ---- 24 accumulators: acc[t][k] = partial dot over this lane's 16 cols ----
        float acc[TPI][NK];
#pragma unroll
        for (int t = 0; t < TPI; ++t)
#pragma unroll
            for (int k = 0; k < NK; ++k) acc[t][k] = 0.0f;

        // ---- per j-chunk: 6 ds_read_b128 of W, then 96 FMAs ----
#pragma unroll
        for (int j = 0; j < 4; ++j) {
            float4 wk[NK];
#pragma unroll
            for (int k = 0; k < NK; ++k)
                wk[k] = wlds[k * 256 + j * 64 + lane];
#pragma unroll
            for (int t = 0; t < TPI; ++t) {
                const float4 xvj = xv[t][j];
#pragma unroll
                for (int k = 0; k < NK; ++k) {
                    float a = acc[t][k];
                    a = fmaf(xvj.x, wk[k].x, a);
                    a = fmaf(xvj.y, wk[k].y, a);
                    a = fmaf(xvj.z, wk[k].z, a);
                    a = fmaf(xvj.w, wk[k].w, a);
                    acc[t][k] = a;
                }
            }
        }

        // ---- step 1: xor 32 — token-pair reduce-scatter (12 shfl) ----
        // after: bit5=0 lanes hold tokens {0,1}, bit5=1 lanes hold {2,3}
        float r[2][NK];
#pragma unroll
        for (int tp = 0; tp < 2; ++tp)
#pragma unroll
            for (int k = 0; k < NK; ++k) {
                float send = hi5 ? acc[tp][k]     : acc[2 + tp][k];
                float keep = hi5 ? acc[2 + tp][k] : acc[tp][k];
                r[tp][k] = keep + __shfl_xor(send, 32, 64);
            }

        // ---- step 2: xor 16 — token reduce-scatter (6 shfl) ----
        // after: 16-lane group g owns token g (sum over lanes {L, L^16, L^32, L^48})
        float z[NK];
#pragma unroll
        for (int k = 0; k < NK; ++k) {
            float send = hi4 ? r[0][k] : r[1][k];
            float keep = hi4 ? r[1][k] : r[0][k];
            z[k] = keep + __shfl_xor(send, 16, 64);
        }

        // ---- steps 3-6: butterfly within the 16-lane group (24 shfl) ----
#pragma unroll
        for (int off = 8; off >= 1; off >>= 1)
#pragma unroll
            for (int k = 0; k < NK; ++k)
                z[k] += __shfl_xor(z[k], off, 64);

        // ---- epilogue: lanes p<8 of each group handle proto p of token tloc ----
        if (pidx < NPROTO) {
            float zz[NK];
            float nrm2 = 0.0f;
#pragma unroll
            for (int k = 0; k < NK; ++k) {
                float a = z[k];
                // tanh(a) = sign(a) * (1-e)/(1+e), e = exp(-2|a|) — hw v_exp_f32
                float e = __expf(-2.0f * fabsf(a));
                float th = (1.0f - e) / (1.0f + e);
                zz[k] = copysignf(th, a);
                nrm2 = fmaf(zz[k], zz[k], nrm2);
            }
            float inv = 1.0f / fmaxf(sqrtf(nrm2), 1e-6f);
            float dot = (zz[0]*p[0] + zz[1]*p[1] + zz[2]*p[2] +
                         zz[3]*p[3] + zz[4]*p[4] + zz[5]*p[5]) * inv;
            float logit = -hs * (6.0f - dot * 6.0f) * 0.5f;
            // softmax over the 8 proto lanes (xor 1,2,4 stays in the subgroup)
            float m = logit;
            m = fmaxf(m, __shfl_xor(m, 1, 64));
            m = fmaxf(m, __shfl_xor(m, 2, 64));
            m = fmaxf(m, __shfl_xor(m, 4, 64));
            float e = __expf(logit - m);
            float s = e;
            s += __shfl_xor(s, 1, 64);
            s += __shfl_xor(s, 2, 64);
            s += __shfl_xor(s, 4, 64);
            out[(size_t)(tb + tloc) * NPROTO + pidx] = e / s;
        }
    }
}

extern "C" void kernel_launch(void* const* d_in, const int* in_sizes, int n_in,
                              void* d_out, int out_size, void* d_ws, size_t ws_size,
                              hipStream_t stream) {
    const float* x      = (const float*)d_in[0];
    const float* W      = (const float*)d_in[1];
    const float* protos = (const float*)d_in[2];
    const float* hs     = (const float*)d_in[3];
    float* out = (float*)d_out;

    const int n_tokens = in_sizes[0] / DIM;   // 32768
    const int blocks = 1024;                  // 4096 waves x 4 tokens x 2 iters = 32768
    const int threads = 256;
    const int n_waves = blocks * (threads / 64);

    q6_fused_kernel<<<blocks, threads, 0, stream>>>(
        x, W, protos, hs, out, n_tokens, n_waves);
}